// Round 22
// baseline (126.188 us; speedup 1.0000x reference)
//
#include <hip/hip_runtime.h>

typedef unsigned short u16;
typedef __attribute__((ext_vector_type(8))) short short8;
typedef __attribute__((ext_vector_type(4))) short s16x4;
typedef __attribute__((ext_vector_type(4))) float f32x4;
typedef __attribute__((ext_vector_type(4))) u16 u16x4;

#define GPTR(p) ((const __attribute__((address_space(1))) void*)(p))
#define LPTR(p) ((__attribute__((address_space(3))) void*)(p))

#if __has_builtin(__builtin_amdgcn_mfma_f32_16x16x16bf16_1k)
#define MFMA16x16(a, b, c) __builtin_amdgcn_mfma_f32_16x16x16bf16_1k(a, b, c, 0, 0, 0)
#elif __has_builtin(__builtin_amdgcn_mfma_f32_16x16x16_bf16)
#define MFMA16x16(a, b, c) __builtin_amdgcn_mfma_f32_16x16x16_bf16(a, b, c, 0, 0, 0)
#else
__host__ __device__ static inline f32x4 MFMA16x16_host_stub(s16x4, s16x4, f32x4 c) { return c; }
#define MFMA16x16(a, b, c) MFMA16x16_host_stub(a, b, c)
#endif

__device__ __forceinline__ u16 f2bf(float f) {
    union { float f; unsigned u; } a; a.f = f;
    unsigned r = a.u + 0x7FFFu + ((a.u >> 16) & 1u);  // RNE
    return (u16)(r >> 16);
}

// ---------------- K0: fused f32 -> bf16 convert (x then qkv_w) ----------------
__global__ __launch_bounds__(256) void cvt_fused_kernel(const float* __restrict__ xin,
                                                        const float* __restrict__ win,
                                                        u16* __restrict__ xout,
                                                        u16* __restrict__ wout) {
    int i = (blockIdx.x * 256 + threadIdx.x) * 4;
    const float* src;
    u16* dst;
    int j;
    if (i < 4841472) {
        src = xin; dst = xout; j = i;
    } else {
        src = win; dst = wout; j = i - 4841472;
    }
    f32x4 v = *(const f32x4*)(src + j);
    u16x4 o;
#pragma unroll
    for (int k = 0; k < 4; ++k) o[k] = f2bf(v[k]);
    *(u16x4*)(dst + j) = o;
}

// ---------------- K1: QKV GEMM 6400x2304x768 — 8-phase, minimal-correct vmcnt ----------------
// Per-wave queue at g0 entry (steady, oldest->newest):
//   [Al(T),Bl(T),Ah(T),Bh(T),Al(T+1),Bl(T+1)] = 12 loads (each STG = 2 loads/wave).
// VM(8)@g0 retires Al(T),Bl(T) (what g0 reads; issued 2 iters ago -> free).
// After g0 issues Ah(T+1): 10 outstanding; VM(6)@g1 retires Ah(T),Bh(T) (what
// g1/g2/g3 read; issued 1 iter ago -> near-free). Tail T=11: VM(4)@g0, VM(0)@g1.
// (R21's VM(4)@g0 was correct but waited on 2-phase-old loads: +4.7us. R20's
// VM(8)+VM(8) left g1's Bh(T) read formally uncovered.)
__global__ __launch_bounds__(512, 2) void qkv_gemm_kernel(
    const u16* __restrict__ A,       // [6400][768] bf16 x
    const u16* __restrict__ Bm,      // [2304][768] bf16 qkv_w
    const float* __restrict__ bias,  // [2304]
    u16* __restrict__ qb, u16* __restrict__ kb, u16* __restrict__ vb) {
    __shared__ __align__(16) u16 As[2][256 * 64];  // 64 KB
    __shared__ __align__(16) u16 Bs[2][256 * 64];  // 64 KB
    const int tid = threadIdx.x;
    const int w = tid >> 6, l = tid & 63;
    const int wy = w >> 2, wx = w & 3;   // 2 M-waves x 4 N-waves
    const int dl = l & 15, g4 = l >> 4;
    const int fr = (dl & 7) << 4;

    // bijective XCD chunking: nwg=225, q=28, r=1
    const int wg = blockIdx.x;
    const int xcd = wg & 7, pos = wg >> 3;
    const int id2 = (xcd < 1 ? xcd * 29 : 29 + (xcd - 1) * 28) + pos;
    const int bm = id2 / 9, bn = id2 % 9;

#define STG(tau, k)                                                                          \
    if ((tau) < 12) {                                                                        \
        const u16* P = ((k) & 1) ? Bm : A;                                                   \
        const int tb = ((k) & 1) ? bn : bm;                                                  \
        char* Lb = (char*)(((k) & 1) ? Bs[(tau) & 1] : As[(tau) & 1]);                       \
        _Pragma("unroll")                                                                    \
        for (int j = 0; j < 2; ++j) {                                                        \
            int c = j * 512 + tid;                                                           \
            int row = (((k) >> 1) << 7) + (c >> 3);                                          \
            int cs = ((c & 7) << 4) ^ ((row & 7) << 4);                                      \
            __builtin_amdgcn_global_load_lds(                                                \
                GPTR((const char*)(P + (size_t)(tb * 256 + row) * 768 + (tau) * 64) + cs),   \
                LPTR(Lb + row * 128 + ((c & 7) << 4)), 16, 0, 0);                            \
        }                                                                                    \
    }

#define RD_A(qm, Tb)                                                                         \
    _Pragma("unroll")                                                                        \
    for (int mi = 0; mi < 4; ++mi)                                                           \
    _Pragma("unroll")                                                                        \
        for (int s = 0; s < 2; ++s)                                                          \
            af[mi][s] = *(const short8*)((const char*)As[(Tb)] +                             \
                ((qm) * 128 + wy * 64 + mi * 16 + dl) * 128 + (((s << 6) | (g4 << 4)) ^ fr));

#define RD_B(qn, Tb)                                                                         \
    _Pragma("unroll")                                                                        \
    for (int ni = 0; ni < 2; ++ni)                                                           \
    _Pragma("unroll")                                                                        \
        for (int s = 0; s < 2; ++s)                                                          \
            bf[ni][s] = *(const short8*)((const char*)Bs[(Tb)] +                             \
                ((qn) * 128 + wx * 32 + ni * 16 + dl) * 128 + (((s << 6) | (g4 << 4)) ^ fr));

#define MM(qm, qn)                                                                           \
    __builtin_amdgcn_s_setprio(1);                                                           \
    _Pragma("unroll")                                                                        \
    for (int s = 0; s < 2; ++s)                                                              \
    _Pragma("unroll")                                                                        \
        for (int mi = 0; mi < 4; ++mi)                                                       \
        _Pragma("unroll")                                                                    \
            for (int ni = 0; ni < 2; ++ni)                                                   \
                acc[qm][qn][mi][ni] = __builtin_amdgcn_mfma_f32_16x16x32_bf16(               \
                    af[mi][s], bf[ni][s], acc[qm][qn][mi][ni], 0, 0, 0);                     \
    __builtin_amdgcn_s_setprio(0);

#define FENCE asm volatile("" ::: "memory")
#define VM(n) asm volatile("s_waitcnt vmcnt(" #n ")" ::: "memory")
#define BAR __builtin_amdgcn_s_barrier()

    f32x4 acc[2][2][4][2] = {};
    short8 af[4][2], bf[2][2];

    // prologue: Al0 Bl0 Ah0 Bh0 Al1 Bl1 -> 12 loads in flight
    STG(0, 0) STG(0, 1) STG(0, 2) STG(0, 3) STG(1, 0) STG(1, 1)

#pragma unroll 1
    for (int T = 0; T < 12; ++T) {
        const int Tb = T & 1;
        // g0: reads Al(T),Bl(T) -- retire the 4 oldest
        if (T < 11) { VM(8); } else { VM(4); }
        BAR; FENCE;
        RD_A(0, Tb) RD_B(0, Tb)
        STG(T + 1, 2)
        MM(0, 0)
        FENCE;
        // g1: reads Bh(T) (g2/g3 read Ah(T)/Bh(T) too) -- retire Ah(T),Bh(T)
        if (T < 11) { VM(6); } else { VM(0); }
        BAR; FENCE;
        RD_B(1, Tb)
        STG(T + 1, 3)
        MM(0, 1)
        FENCE; BAR; FENCE;
        RD_A(1, Tb) RD_B(0, Tb)
        STG(T + 2, 0)
        MM(1, 0)
        FENCE; BAR; FENCE;
        RD_B(1, Tb)
        STG(T + 2, 1)
        MM(1, 1)
        FENCE;
    }
#undef STG
#undef RD_A
#undef RD_B
#undef MM

    // epilogue: split into q/k/v (B,H,N,D) bf16; SCALE folded into q
#pragma unroll
    for (int qn = 0; qn < 2; ++qn)
#pragma unroll
        for (int ni = 0; ni < 2; ++ni) {
            int col = bn * 256 + qn * 128 + wx * 32 + ni * 16 + dl;
            int s = (col >= 1536) ? 2 : (col >= 768) ? 1 : 0;
            int j = col - s * 768;
            int h = j >> 6, d = j & 63;
            float bv = bias[col];
            u16* dst = (s == 0) ? qb : (s == 1) ? kb : vb;
            float sc = (s == 0) ? 0.125f : 1.0f;
#pragma unroll
            for (int qm = 0; qm < 2; ++qm)
#pragma unroll
                for (int mi = 0; mi < 4; ++mi)
#pragma unroll
                    for (int r = 0; r < 4; ++r) {
                        int row = bm * 256 + qm * 128 + wy * 64 + mi * 16 + g4 * 4 + r;
                        if (row < 6304) {
                            int bi = row / 197;
                            int n = row - bi * 197;
                            dst[((size_t)(bi * 12 + h) * 197 + n) * 64 + d] =
                                f2bf((acc[qm][qn][mi][ni][r] + bv) * sc);
                        }
                    }
        }
}

// ---------------- K2: attention, ONE block per (b,h), 8 waves, single-stage ----------------
// Defer-normalization (R20) + mask row hoisted out of the chunk loop (loop-invariant).
#define VPAD 212
__global__ __launch_bounds__(512) void attn_kernel(
    const u16* __restrict__ qg_all, const u16* __restrict__ kg_all, const u16* __restrict__ vg_all,
    const int* __restrict__ y, const float* __restrict__ mask_attn,
    u16* __restrict__ omid) {
    __shared__ __align__(16) u16 Ks[208 * 64];    // XOR-swizzled rows
    __shared__ __align__(16) u16 Vst[64 * VPAD];  // V^T, padded rows
    const int bh = blockIdx.x;
    const int b = bh / 12, h = bh % 12;
    const int tid = threadIdx.x, w = tid >> 6, l = tid & 63;
    const int dl = l & 15, g = l >> 4;
    const size_t base = (size_t)bh * 197 * 64;
    const u16* qg = qg_all + base;
    const u16* kg = kg_all + base;
    const u16* vg = vg_all + base;
    const short8 zero8 = {0, 0, 0, 0, 0, 0, 0, 0};
    const int ycls = y[b];

    // hoist mask row (per-lane slices d = db*16 + g*4, invariant across chunks)
    f32x4 mvh[4];
#pragma unroll
    for (int db = 0; db < 4; ++db)
        mvh[db] = *(const f32x4*)(mask_attn + ((size_t)ycls * 12 + h) * 64 + db * 16 + g * 4);

    for (int c = tid; c < 208 * 8; c += 512) {  // K tile, swizzled, zero pad rows 197..207
        int row = c >> 3, colb = (c & 7) * 16;
        short8 val = zero8;
        if (row < 197) val = *(const short8*)(kg + row * 64 + (c & 7) * 8);
        int bo = (row * 128 + colb) ^ ((row & 7) << 4);
        *(short8*)((char*)Ks + bo) = val;
    }
    for (int c = tid; c < 208 * 8; c += 512) {  // V transposed, zero pad keys 197..207
        int row = c >> 3, col = (c & 7) * 8;
        short8 val = zero8;
        if (row < 197) val = *(const short8*)(vg + row * 64 + col);
#pragma unroll
        for (int j = 0; j < 8; ++j) Vst[(col + j) * VPAD + row] = (u16)val[j];
    }
    __syncthreads();

    for (int ci = w; ci < 13; ci += 8) {  // 8 waves: 5 waves x2 chunks, 3 waves x1
        int qrow = ci * 16 + dl;
        const u16* qr = qg + (size_t)qrow * 64 + g * 8;
        short8 q0 = *(const short8*)(qr);
        short8 q1 = *(const short8*)(qr + 32);

        f32x4 sc[13];
#pragma unroll
        for (int jb = 0; jb < 13; ++jb) {
            int krow = jb * 16 + dl;
            int sw = (krow & 7) << 4;
            short8 k0 = *(const short8*)((const char*)Ks + ((krow * 128 + g * 16) ^ sw));
            short8 k1 = *(const short8*)((const char*)Ks + ((krow * 128 + 64 + g * 16) ^ sw));
            f32x4 t = {0.f, 0.f, 0.f, 0.f};
            t = __builtin_amdgcn_mfma_f32_16x16x32_bf16(k0, q0, t, 0, 0, 0);
            t = __builtin_amdgcn_mfma_f32_16x16x32_bf16(k1, q1, t, 0, 0, 0);
            sc[jb] = t;
        }
#pragma unroll
        for (int r = 0; r < 4; ++r)
            if (192 + g * 4 + r >= 197) sc[12][r] = -1e30f;

        float mx = -1e30f;
#pragma unroll
        for (int jb = 0; jb < 13; ++jb)
#pragma unroll
            for (int r = 0; r < 4; ++r) mx = fmaxf(mx, sc[jb][r]);
        mx = fmaxf(mx, __shfl_xor(mx, 16));
        mx = fmaxf(mx, __shfl_xor(mx, 32));
        float ssum = 0.f;
#pragma unroll
        for (int jb = 0; jb < 13; ++jb)
#pragma unroll
            for (int r = 0; r < 4; ++r) {
                float e = __expf(sc[jb][r] - mx);
                sc[jb][r] = e;
                ssum += e;
            }
        ssum += __shfl_xor(ssum, 16);
        ssum += __shfl_xor(ssum, 32);
        float inv = 1.0f / ssum;

        s16x4 pb[13];  // UNNORMALIZED P (exp values in [0,1])
#pragma unroll
        for (int jb = 0; jb < 13; ++jb) {
            s16x4 pv;
#pragma unroll
            for (int r = 0; r < 4; ++r) pv[r] = (short)f2bf(sc[jb][r]);
            pb[jb] = pv;
        }

        // Uniform whole-wave MFMA; only the store is per-lane predicated (R5 lesson).
        // inv is per-lane (output col q = dl) -> folded into the mask multiply.
#pragma unroll
        for (int db = 0; db < 4; ++db) {
            f32x4 o = {0.f, 0.f, 0.f, 0.f};
#pragma unroll
            for (int jb = 0; jb < 13; ++jb) {
                s16x4 va = *(const s16x4*)&Vst[(db * 16 + dl) * VPAD + jb * 16 + g * 4];
                o = MFMA16x16(va, pb[jb], o);
            }
            if (qrow < 197) {
                int d = db * 16 + g * 4;
                u16x4 ov;
#pragma unroll
                for (int r = 0; r < 4; ++r) ov[r] = f2bf(o[r] * inv * mvh[db][r]);
                *(u16x4*)(omid + ((size_t)(b * 256 + qrow)) * 768 + h * 64 + d) = ov;
            }
        }
    }
}

// ---------------- K4: proj GEMM, 256(M=197pad) x 64(N), BK=64 (R12/R18 verbatim) ----------------
__global__ __launch_bounds__(512, 4) void proj_gemm_kernel(
    const u16* __restrict__ A,          // omid [32][256][768] bf16
    const float* __restrict__ proj_w,   // [768][768] f32
    const float* __restrict__ mask_proj,// [100][768][768] f32
    const int* __restrict__ y,
    const float* __restrict__ bias,     // [768]
    float* __restrict__ out) {          // [32][197][768] f32
    __shared__ __align__(16) u16 Ap[2][256 * 64];  // 64 KB
    __shared__ __align__(16) u16 Bp[2][64 * 64];   // 16 KB
    const int tid = threadIdx.x;
    const int w = tid >> 6, l = tid & 63;
    const int wy = w >> 1, wx = w & 1;   // 4 M-waves x 2 N-waves (64x32 each)
    const int dl = l & 15, g4 = l >> 4;
    const int fr = (dl & 7) << 4;

    // bijective XCD chunking: nwg=384, q=48, r=0; bn-fast -> omid panel L2 reuse
    const int wg = blockIdx.x;
    const int id2 = (wg & 7) * 48 + (wg >> 3);
    const int b = id2 / 12, bn = id2 % 12;
    const size_t mbase = (size_t)y[b] * 589824;

    const int brow = tid >> 3;           // B-stage: N-row 0..63
    const int bcolf = (tid & 7) * 8;     // 8 f32 K-cols per thread
    const int bcb = bcolf * 2;           // byte col in bf16 LDS row
    const int bsw = (brow & 7) << 4;

    f32x4 pw[2], pm[2];

#define PROJ_LOADB(kt)                                                              \
    {                                                                               \
        size_t off = (size_t)(bn * 64 + brow) * 768 + (kt) + bcolf;                 \
        pw[0] = *(const f32x4*)(proj_w + off);                                      \
        pw[1] = *(const f32x4*)(proj_w + off + 4);                                  \
        pm[0] = *(const f32x4*)(mask_proj + mbase + off);                           \
        pm[1] = *(const f32x4*)(mask_proj + mbase + off + 4);                       \
    }

#define PROJ_WRITEB(bi)                                                             \
    {                                                                               \
        short8 o0;                                                                  \
        _Pragma("unroll")                                                           \
        for (int j = 0; j < 4; ++j) {                                               \
            o0[j] = (short)f2bf(pw[0][j] * pm[0][j]);                               \
            o0[4 + j] = (short)f2bf(pw[1][j] * pm[1][j]);                           \
        }                                                                           \
        *(short8*)((char*)Bp[bi] + brow * 128 + (bcb ^ bsw)) = o0;                  \
    }

#define PROJ_STAGEA(bi, kt)                                                         \
    {                                                                               \
        _Pragma("unroll")                                                           \
        for (int cc = 0; cc < 4; ++cc) {                                            \
            int c = cc * 512 + tid;                                                 \
            int row = c >> 3;                                                       \
            int cs = ((c & 7) << 4) ^ ((row & 7) << 4);                             \
            __builtin_amdgcn_global_load_lds(                                       \
                GPTR((const char*)(A + (size_t)(b * 256 + row) * 768 + (kt)) + cs), \
                LPTR((char*)Ap[bi] + c * 16), 16, 0, 0);                            \
        }                                                                           \
    }

    f32x4 acc[4][2] = {};
    PROJ_LOADB(0)
    PROJ_STAGEA(0, 0)
    PROJ_WRITEB(0)
    __syncthreads();
    int cur = 0;
#pragma unroll 1
    for (int t = 0; t < 12; ++t) {
        if (t < 11) {
            PROJ_STAGEA(cur ^ 1, (t + 1) * 64)  // async A prefetch
            PROJ_LOADB((t + 1) * 64)            // B f32 loads issue early...
        }
#pragma unroll
        for (int s = 0; s < 2; ++s) {
            const int ce = ((s << 6) | (g4 << 4)) ^ fr;
            short8 af[4], bf[2];
#pragma unroll
            for (int mi = 0; mi < 4; ++mi)
                af[mi] = *(const short8*)((const char*)Ap[cur] + (wy * 64 + mi * 16 + dl) * 128 + ce);
#pragma unroll
            for (int ni = 0; ni < 2; ++ni)
                bf[ni] = *(const short8*)((const char*)Bp[cur] + (wx * 32 + ni * 16 + dl) * 128 + ce);
#pragma unroll
            for (int mi = 0; mi < 4; ++mi)
#pragma unroll
                for (int ni = 0; ni < 2; ++ni)
                    acc[mi][ni] = __builtin_amdgcn_mfma_f32_16x16x32_bf16(af[mi], bf[ni], acc[mi][ni], 0, 0, 0);
        }
        if (t < 11) PROJ_WRITEB(cur ^ 1)        // ...convert+write late (latency hidden)
        __syncthreads();
        cur ^= 1;
    }

#pragma unroll
    for (int ni = 0; ni < 2; ++ni) {
        int col = bn * 64 + wx * 32 + ni * 16 + dl;
        float bv = bias[col];
#pragma unroll
        for (int mi = 0; mi < 4; ++mi) {
#pragma unroll
            for (int r = 0; r < 4; ++r) {
                int row = wy * 64 + mi * 16 + g4 * 4 + r;
                if (row < 197)
                    out[((size_t)b * 197 + row) * 768 + col] = acc[mi][ni][r] + bv;
            }
        }
    }
#undef PROJ_LOADB
#undef PROJ_WRITEB
#undef PROJ_STAGEA
}

extern "C" void kernel_launch(void* const* d_in, const int* in_sizes, int n_in,
                              void* d_out, int out_size, void* d_ws, size_t ws_size,
                              hipStream_t stream) {
    const float* x = (const float*)d_in[0];
    const int* y = (const int*)d_in[1];
    const float* qkv_w = (const float*)d_in[2];
    const float* qkv_b = (const float*)d_in[3];
    const float* proj_w = (const float*)d_in[4];
    const float* proj_b = (const float*)d_in[5];
    const float* mask_attn = (const float*)d_in[6];
    const float* mask_proj = (const float*)d_in[7];
    float* out = (float*)d_out;

    // workspace layout (bf16 = u16), ~55.3 MB
    u16* xb = (u16*)d_ws;                       // [6400][768]
    u16* wqkvb = xb + (size_t)6400 * 768;       // [2304][768]
    u16* qb = wqkvb + (size_t)2304 * 768;       // [76288][64]
    u16* kb = qb + (size_t)76288 * 64;
    u16* vb = kb + (size_t)76288 * 64;
    u16* omid = vb + (size_t)76288 * 64;        // [32][256][768]

    cvt_fused_kernel<<<6456, 256, 0, stream>>>(x, qkv_w, xb, wqkvb);
    qkv_gemm_kernel<<<225, 512, 0, stream>>>(xb, wqkvb, qkv_b, qb, kb, vb);
    attn_kernel<<<384, 512, 0, stream>>>(qb, kb, vb, y, mask_attn, omid);
    proj_gemm_kernel<<<384, 512, 0, stream>>>(omid, proj_w, mask_proj, y, proj_b, out);
}

// Round 23
// 124.017 us; speedup vs baseline: 1.0175x; 1.0175x over previous
//
#include <hip/hip_runtime.h>

typedef unsigned short u16;
typedef __attribute__((ext_vector_type(8))) short short8;
typedef __attribute__((ext_vector_type(4))) short s16x4;
typedef __attribute__((ext_vector_type(4))) float f32x4;
typedef __attribute__((ext_vector_type(4))) u16 u16x4;

#define GPTR(p) ((const __attribute__((address_space(1))) void*)(p))
#define LPTR(p) ((__attribute__((address_space(3))) void*)(p))

#if __has_builtin(__builtin_amdgcn_mfma_f32_16x16x16bf16_1k)
#define MFMA16x16(a, b, c) __builtin_amdgcn_mfma_f32_16x16x16bf16_1k(a, b, c, 0, 0, 0)
#elif __has_builtin(__builtin_amdgcn_mfma_f32_16x16x16_bf16)
#define MFMA16x16(a, b, c) __builtin_amdgcn_mfma_f32_16x16x16_bf16(a, b, c, 0, 0, 0)
#else
__host__ __device__ static inline f32x4 MFMA16x16_host_stub(s16x4, s16x4, f32x4 c) { return c; }
#define MFMA16x16(a, b, c) MFMA16x16_host_stub(a, b, c)
#endif

__device__ __forceinline__ u16 f2bf(float f) {
    union { float f; unsigned u; } a; a.f = f;
    unsigned r = a.u + 0x7FFFu + ((a.u >> 16) & 1u);  // RNE
    return (u16)(r >> 16);
}

// ---------------- K0: fused f32 -> bf16 convert (x then qkv_w) ----------------
__global__ __launch_bounds__(256) void cvt_fused_kernel(const float* __restrict__ xin,
                                                        const float* __restrict__ win,
                                                        u16* __restrict__ xout,
                                                        u16* __restrict__ wout) {
    int i = (blockIdx.x * 256 + threadIdx.x) * 4;
    const float* src;
    u16* dst;
    int j;
    if (i < 4841472) {
        src = xin; dst = xout; j = i;
    } else {
        src = win; dst = wout; j = i - 4841472;
    }
    f32x4 v = *(const f32x4*)(src + j);
    u16x4 o;
#pragma unroll
    for (int k = 0; k < 4; ++k) o[k] = f2bf(v[k]);
    *(u16x4*)(dst + j) = o;
}

// ---------------- K1: QKV GEMM 6400x2304x768, 256x256 tile, BK=64, 8 waves ----------------
// R12-exact 2-phase: __syncthreads (= vmcnt(0)+barrier) drains the prefetch once per
// K-tile -- correct BY CONSTRUCTION. vmcnt ledger (R20-R22): the racy 8ph = 116.7,
// correct 8ph variants = 121.4/126.2 (tile T's high halves complete only between
// phases g1-g2; a correct wait there always stalls; 2-tiles-ahead needs 192KB LDS).
// 2-phase is the fastest CORRECT scheme at this shape (~47us).
__global__ __launch_bounds__(512, 2) void qkv_gemm_kernel(
    const u16* __restrict__ A,       // [6400][768] bf16 x
    const u16* __restrict__ Bm,      // [2304][768] bf16 qkv_w
    const float* __restrict__ bias,  // [2304]
    u16* __restrict__ qb, u16* __restrict__ kb, u16* __restrict__ vb) {
    __shared__ __align__(16) u16 As[2][256 * 64];  // 64 KB
    __shared__ __align__(16) u16 Bs[2][256 * 64];  // 64 KB
    const int tid = threadIdx.x;
    const int w = tid >> 6, l = tid & 63;
    const int wy = w >> 2, wx = w & 3;   // 2 M-waves x 4 N-waves (128x64 each)
    const int dl = l & 15, g4 = l >> 4;
    const int fr = (dl & 7) << 4;

    // bijective XCD chunking: nwg=225, q=28, r=1; bn-fast -> A panel L2 reuse
    const int wg = blockIdx.x;
    const int xcd = wg & 7, pos = wg >> 3;
    const int id2 = (xcd < 1 ? xcd * 29 : 29 + (xcd - 1) * 28) + pos;
    const int bm = id2 / 9, bn = id2 % 9;

    f32x4 acc[8][4] = {};

#define QKV_STAGE(bi, kt)                                                                   \
    {                                                                                       \
        _Pragma("unroll")                                                                   \
        for (int cc = 0; cc < 4; ++cc) {                                                    \
            int c = w * 256 + cc * 64 + l;                                                  \
            int row = c >> 3;                                                               \
            int cs = ((c & 7) << 4) ^ ((row & 7) << 4);                                     \
            __builtin_amdgcn_global_load_lds(                                               \
                GPTR((const char*)(A + (size_t)(bm * 256 + row) * 768 + (kt)) + cs),        \
                LPTR((char*)As[bi] + c * 16), 16, 0, 0);                                    \
            __builtin_amdgcn_global_load_lds(                                               \
                GPTR((const char*)(Bm + (size_t)(bn * 256 + row) * 768 + (kt)) + cs),       \
                LPTR((char*)Bs[bi] + c * 16), 16, 0, 0);                                    \
        }                                                                                   \
    }

    QKV_STAGE(0, 0)
    __syncthreads();
    int cur = 0;
#pragma unroll 1
    for (int t = 0; t < 12; ++t) {
        if (t < 11) QKV_STAGE(cur ^ 1, (t + 1) * 64)  // prefetch overlaps compute
#pragma unroll
        for (int s = 0; s < 2; ++s) {
            const int ce = ((s << 6) | (g4 << 4)) ^ fr;
            short8 af[8], bf[4];
#pragma unroll
            for (int mi = 0; mi < 8; ++mi)
                af[mi] = *(const short8*)((const char*)As[cur] + (wy * 128 + mi * 16 + dl) * 128 + ce);
#pragma unroll
            for (int ni = 0; ni < 4; ++ni)
                bf[ni] = *(const short8*)((const char*)Bs[cur] + (wx * 64 + ni * 16 + dl) * 128 + ce);
#pragma unroll
            for (int mi = 0; mi < 8; ++mi)
#pragma unroll
                for (int ni = 0; ni < 4; ++ni)
                    acc[mi][ni] = __builtin_amdgcn_mfma_f32_16x16x32_bf16(af[mi], bf[ni], acc[mi][ni], 0, 0, 0);
        }
        __syncthreads();
        cur ^= 1;
    }
#undef QKV_STAGE

    // epilogue: split into q/k/v (B,H,N,D) bf16; SCALE folded into q
#pragma unroll
    for (int ni = 0; ni < 4; ++ni) {
        int col = bn * 256 + wx * 64 + ni * 16 + dl;
        int s = (col >= 1536) ? 2 : (col >= 768) ? 1 : 0;
        int j = col - s * 768;
        int h = j >> 6, d = j & 63;
        float bv = bias[col];
        u16* dst = (s == 0) ? qb : (s == 1) ? kb : vb;
        float sc = (s == 0) ? 0.125f : 1.0f;
#pragma unroll
        for (int mi = 0; mi < 8; ++mi) {
#pragma unroll
            for (int r = 0; r < 4; ++r) {
                int row = bm * 256 + wy * 128 + mi * 16 + g4 * 4 + r;
                if (row < 6304) {
                    int bi = row / 197;
                    int n = row - bi * 197;
                    dst[((size_t)(bi * 12 + h) * 197 + n) * 64 + d] = f2bf((acc[mi][ni][r] + bv) * sc);
                }
            }
        }
    }
}

// ---------------- K2: attention, ONE block per (b,h), 8 waves, single-stage ----------------
// Defer-normalization (R20) + mask row hoisted (R21). Single K/V staging per head.
#define VPAD 212
__global__ __launch_bounds__(512) void attn_kernel(
    const u16* __restrict__ qg_all, const u16* __restrict__ kg_all, const u16* __restrict__ vg_all,
    const int* __restrict__ y, const float* __restrict__ mask_attn,
    u16* __restrict__ omid) {
    __shared__ __align__(16) u16 Ks[208 * 64];    // XOR-swizzled rows
    __shared__ __align__(16) u16 Vst[64 * VPAD];  // V^T, padded rows
    const int bh = blockIdx.x;
    const int b = bh / 12, h = bh % 12;
    const int tid = threadIdx.x, w = tid >> 6, l = tid & 63;
    const int dl = l & 15, g = l >> 4;
    const size_t base = (size_t)bh * 197 * 64;
    const u16* qg = qg_all + base;
    const u16* kg = kg_all + base;
    const u16* vg = vg_all + base;
    const short8 zero8 = {0, 0, 0, 0, 0, 0, 0, 0};
    const int ycls = y[b];

    // hoist mask row (per-lane slices d = db*16 + g*4, invariant across chunks)
    f32x4 mvh[4];
#pragma unroll
    for (int db = 0; db < 4; ++db)
        mvh[db] = *(const f32x4*)(mask_attn + ((size_t)ycls * 12 + h) * 64 + db * 16 + g * 4);

    for (int c = tid; c < 208 * 8; c += 512) {  // K tile, swizzled, zero pad rows 197..207
        int row = c >> 3, colb = (c & 7) * 16;
        short8 val = zero8;
        if (row < 197) val = *(const short8*)(kg + row * 64 + (c & 7) * 8);
        int bo = (row * 128 + colb) ^ ((row & 7) << 4);
        *(short8*)((char*)Ks + bo) = val;
    }
    for (int c = tid; c < 208 * 8; c += 512) {  // V transposed, zero pad keys 197..207
        int row = c >> 3, col = (c & 7) * 8;
        short8 val = zero8;
        if (row < 197) val = *(const short8*)(vg + row * 64 + col);
#pragma unroll
        for (int j = 0; j < 8; ++j) Vst[(col + j) * VPAD + row] = (u16)val[j];
    }
    __syncthreads();

    for (int ci = w; ci < 13; ci += 8) {  // 8 waves: 5 waves x2 chunks, 3 waves x1
        int qrow = ci * 16 + dl;
        const u16* qr = qg + (size_t)qrow * 64 + g * 8;
        short8 q0 = *(const short8*)(qr);
        short8 q1 = *(const short8*)(qr + 32);

        f32x4 sc[13];
#pragma unroll
        for (int jb = 0; jb < 13; ++jb) {
            int krow = jb * 16 + dl;
            int sw = (krow & 7) << 4;
            short8 k0 = *(const short8*)((const char*)Ks + ((krow * 128 + g * 16) ^ sw));
            short8 k1 = *(const short8*)((const char*)Ks + ((krow * 128 + 64 + g * 16) ^ sw));
            f32x4 t = {0.f, 0.f, 0.f, 0.f};
            t = __builtin_amdgcn_mfma_f32_16x16x32_bf16(k0, q0, t, 0, 0, 0);
            t = __builtin_amdgcn_mfma_f32_16x16x32_bf16(k1, q1, t, 0, 0, 0);
            sc[jb] = t;
        }
#pragma unroll
        for (int r = 0; r < 4; ++r)
            if (192 + g * 4 + r >= 197) sc[12][r] = -1e30f;

        float mx = -1e30f;
#pragma unroll
        for (int jb = 0; jb < 13; ++jb)
#pragma unroll
            for (int r = 0; r < 4; ++r) mx = fmaxf(mx, sc[jb][r]);
        mx = fmaxf(mx, __shfl_xor(mx, 16));
        mx = fmaxf(mx, __shfl_xor(mx, 32));
        float ssum = 0.f;
#pragma unroll
        for (int jb = 0; jb < 13; ++jb)
#pragma unroll
            for (int r = 0; r < 4; ++r) {
                float e = __expf(sc[jb][r] - mx);
                sc[jb][r] = e;
                ssum += e;
            }
        ssum += __shfl_xor(ssum, 16);
        ssum += __shfl_xor(ssum, 32);
        float inv = 1.0f / ssum;

        s16x4 pb[13];  // UNNORMALIZED P (exp values in [0,1])
#pragma unroll
        for (int jb = 0; jb < 13; ++jb) {
            s16x4 pv;
#pragma unroll
            for (int r = 0; r < 4; ++r) pv[r] = (short)f2bf(sc[jb][r]);
            pb[jb] = pv;
        }

        // Uniform whole-wave MFMA; only the store is per-lane predicated (R5 lesson).
        // inv is per-lane (output col q = dl) -> folded into the mask multiply.
#pragma unroll
        for (int db = 0; db < 4; ++db) {
            f32x4 o = {0.f, 0.f, 0.f, 0.f};
#pragma unroll
            for (int jb = 0; jb < 13; ++jb) {
                s16x4 va = *(const s16x4*)&Vst[(db * 16 + dl) * VPAD + jb * 16 + g * 4];
                o = MFMA16x16(va, pb[jb], o);
            }
            if (qrow < 197) {
                int d = db * 16 + g * 4;
                u16x4 ov;
#pragma unroll
                for (int r = 0; r < 4; ++r) ov[r] = f2bf(o[r] * inv * mvh[db][r]);
                *(u16x4*)(omid + ((size_t)(b * 256 + qrow)) * 768 + h * 64 + d) = ov;
            }
        }
    }
}

// ---------------- K4: proj GEMM, 256(M=197pad) x 64(N), BK=64 (R12/R18 verbatim) ----------------
__global__ __launch_bounds__(512, 4) void proj_gemm_kernel(
    const u16* __restrict__ A,          // omid [32][256][768] bf16
    const float* __restrict__ proj_w,   // [768][768] f32
    const float* __restrict__ mask_proj,// [100][768][768] f32
    const int* __restrict__ y,
    const float* __restrict__ bias,     // [768]
    float* __restrict__ out) {          // [32][197][768] f32
    __shared__ __align__(16) u16 Ap[2][256 * 64];  // 64 KB
    __shared__ __align__(16) u16 Bp[2][64 * 64];   // 16 KB
    const int tid = threadIdx.x;
    const int w = tid >> 6, l = tid & 63;
    const int wy = w >> 1, wx = w & 1;   // 4 M-waves x 2 N-waves (64x32 each)
    const int dl = l & 15, g4 = l >> 4;
    const int fr = (dl & 7) << 4;

    // bijective XCD chunking: nwg=384, q=48, r=0; bn-fast -> omid panel L2 reuse
    const int wg = blockIdx.x;
    const int id2 = (wg & 7) * 48 + (wg >> 3);
    const int b = id2 / 12, bn = id2 % 12;
    const size_t mbase = (size_t)y[b] * 589824;

    const int brow = tid >> 3;           // B-stage: N-row 0..63
    const int bcolf = (tid & 7) * 8;     // 8 f32 K-cols per thread
    const int bcb = bcolf * 2;           // byte col in bf16 LDS row
    const int bsw = (brow & 7) << 4;

    f32x4 pw[2], pm[2];

#define PROJ_LOADB(kt)                                                              \
    {                                                                               \
        size_t off = (size_t)(bn * 64 + brow) * 768 + (kt) + bcolf;                 \
        pw[0] = *(const f32x4*)(proj_w + off);                                      \
        pw[1] = *(const f32x4*)(proj_w + off + 4);                                  \
        pm[0] = *(const f32x4*)(mask_proj + mbase + off);                           \
        pm[1] = *(const f32x4*)(mask_proj + mbase + off + 4);                       \
    }

#define PROJ_WRITEB(bi)                                                             \
    {                                                                               \
        short8 o0;                                                                  \
        _Pragma("unroll")                                                           \
        for (int j = 0; j < 4; ++j) {                                               \
            o0[j] = (short)f2bf(pw[0][j] * pm[0][j]);                               \
            o0[4 + j] = (short)f2bf(pw[1][j] * pm[1][j]);                           \
        }                                                                           \
        *(short8*)((char*)Bp[bi] + brow * 128 + (bcb ^ bsw)) = o0;                  \
    }

#define PROJ_STAGEA(bi, kt)                                                         \
    {                                                                               \
        _Pragma("unroll")                                                           \
        for (int cc = 0; cc < 4; ++cc) {                                            \
            int c = cc * 512 + tid;                                                 \
            int row = c >> 3;                                                       \
            int cs = ((c & 7) << 4) ^ ((row & 7) << 4);                             \
            __builtin_amdgcn_global_load_lds(                                       \
                GPTR((const char*)(A + (size_t)(b * 256 + row) * 768 + (kt)) + cs), \
                LPTR((char*)Ap[bi] + c * 16), 16, 0, 0);                            \
        }                                                                           \
    }

    f32x4 acc[4][2] = {};
    PROJ_LOADB(0)
    PROJ_STAGEA(0, 0)
    PROJ_WRITEB(0)
    __syncthreads();
    int cur = 0;
#pragma unroll 1
    for (int t = 0; t < 12; ++t) {
        if (t < 11) {
            PROJ_STAGEA(cur ^ 1, (t + 1) * 64)  // async A prefetch
            PROJ_LOADB((t + 1) * 64)            // B f32 loads issue early...
        }
#pragma unroll
        for (int s = 0; s < 2; ++s) {
            const int ce = ((s << 6) | (g4 << 4)) ^ fr;
            short8 af[4], bf[2];
#pragma unroll
            for (int mi = 0; mi < 4; ++mi)
                af[mi] = *(const short8*)((const char*)Ap[cur] + (wy * 64 + mi * 16 + dl) * 128 + ce);
#pragma unroll
            for (int ni = 0; ni < 2; ++ni)
                bf[ni] = *(const short8*)((const char*)Bp[cur] + (wx * 32 + ni * 16 + dl) * 128 + ce);
#pragma unroll
            for (int mi = 0; mi < 4; ++mi)
#pragma unroll
                for (int ni = 0; ni < 2; ++ni)
                    acc[mi][ni] = __builtin_amdgcn_mfma_f32_16x16x32_bf16(af[mi], bf[ni], acc[mi][ni], 0, 0, 0);
        }
        if (t < 11) PROJ_WRITEB(cur ^ 1)        // ...convert+write late (latency hidden)
        __syncthreads();
        cur ^= 1;
    }

#pragma unroll
    for (int ni = 0; ni < 2; ++ni) {
        int col = bn * 64 + wx * 32 + ni * 16 + dl;
        float bv = bias[col];
#pragma unroll
        for (int mi = 0; mi < 4; ++mi) {
#pragma unroll
            for (int r = 0; r < 4; ++r) {
                int row = wy * 64 + mi * 16 + g4 * 4 + r;
                if (row < 197)
                    out[((size_t)b * 197 + row) * 768 + col] = acc[mi][ni][r] + bv;
            }
        }
    }
#undef PROJ_LOADB
#undef PROJ_WRITEB
#undef PROJ_STAGEA
}

extern "C" void kernel_launch(void* const* d_in, const int* in_sizes, int n_in,
                              void* d_out, int out_size, void* d_ws, size_t ws_size,
                              hipStream_t stream) {
    const float* x = (const float*)d_in[0];
    const int* y = (const int*)d_in[1];
    const float* qkv_w = (const float*)d_in[2];
    const float* qkv_b = (const float*)d_in[3];
    const float* proj_w = (const float*)d_in[4];
    const float* proj_b = (const float*)d_in[5];
    const float* mask_attn = (const float*)d_in[6];
    const float* mask_proj = (const float*)d_in[7];
    float* out = (float*)d_out;

    // workspace layout (bf16 = u16), ~55.3 MB
    u16* xb = (u16*)d_ws;                       // [6400][768]
    u16* wqkvb = xb + (size_t)6400 * 768;       // [2304][768]
    u16* qb = wqkvb + (size_t)2304 * 768;       // [76288][64]
    u16* kb = qb + (size_t)76288 * 64;
    u16* vb = kb + (size_t)76288 * 64;
    u16* omid = vb + (size_t)76288 * 64;        // [32][256][768]

    cvt_fused_kernel<<<6456, 256, 0, stream>>>(x, qkv_w, xb, wqkvb);
    qkv_gemm_kernel<<<225, 512, 0, stream>>>(xb, wqkvb, qkv_b, qb, kb, vb);
    attn_kernel<<<384, 512, 0, stream>>>(qb, kb, vb, y, mask_attn, omid);
    proj_gemm_kernel<<<384, 512, 0, stream>>>(omid, proj_w, mask_proj, y, proj_b, out);
}

// Round 24
// 121.160 us; speedup vs baseline: 1.0415x; 1.0236x over previous
//
#include <hip/hip_runtime.h>

typedef unsigned short u16;
typedef __attribute__((ext_vector_type(8))) short short8;
typedef __attribute__((ext_vector_type(4))) short s16x4;
typedef __attribute__((ext_vector_type(4))) float f32x4;
typedef __attribute__((ext_vector_type(4))) u16 u16x4;

#define GPTR(p) ((const __attribute__((address_space(1))) void*)(p))
#define LPTR(p) ((__attribute__((address_space(3))) void*)(p))

#if __has_builtin(__builtin_amdgcn_mfma_f32_16x16x16bf16_1k)
#define MFMA16x16(a, b, c) __builtin_amdgcn_mfma_f32_16x16x16bf16_1k(a, b, c, 0, 0, 0)
#elif __has_builtin(__builtin_amdgcn_mfma_f32_16x16x16_bf16)
#define MFMA16x16(a, b, c) __builtin_amdgcn_mfma_f32_16x16x16_bf16(a, b, c, 0, 0, 0)
#else
__host__ __device__ static inline f32x4 MFMA16x16_host_stub(s16x4, s16x4, f32x4 c) { return c; }
#define MFMA16x16(a, b, c) MFMA16x16_host_stub(a, b, c)
#endif

__device__ __forceinline__ u16 f2bf(float f) {
    union { float f; unsigned u; } a; a.f = f;
    unsigned r = a.u + 0x7FFFu + ((a.u >> 16) & 1u);  // RNE
    return (u16)(r >> 16);
}

// ---------------- K0: fused f32 -> bf16 convert (x then qkv_w) ----------------
__global__ __launch_bounds__(256) void cvt_fused_kernel(const float* __restrict__ xin,
                                                        const float* __restrict__ win,
                                                        u16* __restrict__ xout,
                                                        u16* __restrict__ wout) {
    int i = (blockIdx.x * 256 + threadIdx.x) * 4;
    const float* src;
    u16* dst;
    int j;
    if (i < 4841472) {
        src = xin; dst = xout; j = i;
    } else {
        src = win; dst = wout; j = i - 4841472;
    }
    f32x4 v = *(const f32x4*)(src + j);
    u16x4 o;
#pragma unroll
    for (int k = 0; k < 4; ++k) o[k] = f2bf(v[k]);
    *(u16x4*)(dst + j) = o;
}

// ---------------- K1: QKV GEMM 6400x2304x768 — 8-phase, single-wait vmcnt ----------------
// MEASURED-BEST CORRECT SCHEME (R21 = 121.4us). Queue at g0 entry (steady):
// [Al(T),Bl(T),Ah(T),Bh(T),Al(T+1),Bl(T+1)] = 12 loads. VM(4)@g0 retires ALL of
// tile T before any phase reads it; no other waits interrupt the 4 MFMA phases.
// Ledger: racy VM(8)+VM(8)=116.7 (g1's Bh(T) read uncovered -- rejected);
// VM(8)+VM(6)@g1=126.2 (stalls mid-pipeline); 2-phase __syncthreads=124.0.
__global__ __launch_bounds__(512, 2) void qkv_gemm_kernel(
    const u16* __restrict__ A,       // [6400][768] bf16 x
    const u16* __restrict__ Bm,      // [2304][768] bf16 qkv_w
    const float* __restrict__ bias,  // [2304]
    u16* __restrict__ qb, u16* __restrict__ kb, u16* __restrict__ vb) {
    __shared__ __align__(16) u16 As[2][256 * 64];  // 64 KB
    __shared__ __align__(16) u16 Bs[2][256 * 64];  // 64 KB
    const int tid = threadIdx.x;
    const int w = tid >> 6, l = tid & 63;
    const int wy = w >> 2, wx = w & 3;   // 2 M-waves x 4 N-waves
    const int dl = l & 15, g4 = l >> 4;
    const int fr = (dl & 7) << 4;

    // bijective XCD chunking: nwg=225, q=28, r=1
    const int wg = blockIdx.x;
    const int xcd = wg & 7, pos = wg >> 3;
    const int id2 = (xcd < 1 ? xcd * 29 : 29 + (xcd - 1) * 28) + pos;
    const int bm = id2 / 9, bn = id2 % 9;

#define STG(tau, k)                                                                          \
    if ((tau) < 12) {                                                                        \
        const u16* P = ((k) & 1) ? Bm : A;                                                   \
        const int tb = ((k) & 1) ? bn : bm;                                                  \
        char* Lb = (char*)(((k) & 1) ? Bs[(tau) & 1] : As[(tau) & 1]);                       \
        _Pragma("unroll")                                                                    \
        for (int j = 0; j < 2; ++j) {                                                        \
            int c = j * 512 + tid;                                                           \
            int row = (((k) >> 1) << 7) + (c >> 3);                                          \
            int cs = ((c & 7) << 4) ^ ((row & 7) << 4);                                      \
            __builtin_amdgcn_global_load_lds(                                                \
                GPTR((const char*)(P + (size_t)(tb * 256 + row) * 768 + (tau) * 64) + cs),   \
                LPTR(Lb + row * 128 + ((c & 7) << 4)), 16, 0, 0);                            \
        }                                                                                    \
    }

#define RD_A(qm, Tb)                                                                         \
    _Pragma("unroll")                                                                        \
    for (int mi = 0; mi < 4; ++mi)                                                           \
    _Pragma("unroll")                                                                        \
        for (int s = 0; s < 2; ++s)                                                          \
            af[mi][s] = *(const short8*)((const char*)As[(Tb)] +                             \
                ((qm) * 128 + wy * 64 + mi * 16 + dl) * 128 + (((s << 6) | (g4 << 4)) ^ fr));

#define RD_B(qn, Tb)                                                                         \
    _Pragma("unroll")                                                                        \
    for (int ni = 0; ni < 2; ++ni)                                                           \
    _Pragma("unroll")                                                                        \
        for (int s = 0; s < 2; ++s)                                                          \
            bf[ni][s] = *(const short8*)((const char*)Bs[(Tb)] +                             \
                ((qn) * 128 + wx * 32 + ni * 16 + dl) * 128 + (((s << 6) | (g4 << 4)) ^ fr));

#define MM(qm, qn)                                                                           \
    __builtin_amdgcn_s_setprio(1);                                                           \
    _Pragma("unroll")                                                                        \
    for (int s = 0; s < 2; ++s)                                                              \
    _Pragma("unroll")                                                                        \
        for (int mi = 0; mi < 4; ++mi)                                                       \
        _Pragma("unroll")                                                                    \
            for (int ni = 0; ni < 2; ++ni)                                                   \
                acc[qm][qn][mi][ni] = __builtin_amdgcn_mfma_f32_16x16x32_bf16(               \
                    af[mi][s], bf[ni][s], acc[qm][qn][mi][ni], 0, 0, 0);                     \
    __builtin_amdgcn_s_setprio(0);

#define FENCE asm volatile("" ::: "memory")
#define VM(n) asm volatile("s_waitcnt vmcnt(" #n ")" ::: "memory")
#define BAR __builtin_amdgcn_s_barrier()

    f32x4 acc[2][2][4][2] = {};
    short8 af[4][2], bf[2][2];

    // prologue: Al0 Bl0 Ah0 Bh0 Al1 Bl1 -> 12 loads in flight
    STG(0, 0) STG(0, 1) STG(0, 2) STG(0, 3) STG(1, 0) STG(1, 1)

#pragma unroll 1
    for (int T = 0; T < 12; ++T) {
        const int Tb = T & 1;
        // single wait covers ALL of tile T's halves (tile T = oldest 8 of 12)
        if (T < 11) { VM(4); } else { VM(0); }
        BAR; FENCE;
        RD_A(0, Tb) RD_B(0, Tb)
        STG(T + 1, 2)
        MM(0, 0)
        FENCE; BAR; FENCE;
        RD_B(1, Tb)
        STG(T + 1, 3)
        MM(0, 1)
        FENCE; BAR; FENCE;
        RD_A(1, Tb) RD_B(0, Tb)
        STG(T + 2, 0)
        MM(1, 0)
        FENCE; BAR; FENCE;
        RD_B(1, Tb)
        STG(T + 2, 1)
        MM(1, 1)
        FENCE;
    }
#undef STG
#undef RD_A
#undef RD_B
#undef MM

    // epilogue: split into q/k/v (B,H,N,D) bf16; SCALE folded into q
#pragma unroll
    for (int qn = 0; qn < 2; ++qn)
#pragma unroll
        for (int ni = 0; ni < 2; ++ni) {
            int col = bn * 256 + qn * 128 + wx * 32 + ni * 16 + dl;
            int s = (col >= 1536) ? 2 : (col >= 768) ? 1 : 0;
            int j = col - s * 768;
            int h = j >> 6, d = j & 63;
            float bv = bias[col];
            u16* dst = (s == 0) ? qb : (s == 1) ? kb : vb;
            float sc = (s == 0) ? 0.125f : 1.0f;
#pragma unroll
            for (int qm = 0; qm < 2; ++qm)
#pragma unroll
                for (int mi = 0; mi < 4; ++mi)
#pragma unroll
                    for (int r = 0; r < 4; ++r) {
                        int row = bm * 256 + qm * 128 + wy * 64 + mi * 16 + g4 * 4 + r;
                        if (row < 6304) {
                            int bi = row / 197;
                            int n = row - bi * 197;
                            dst[((size_t)(bi * 12 + h) * 197 + n) * 64 + d] =
                                f2bf((acc[qm][qn][mi][ni][r] + bv) * sc);
                        }
                    }
        }
}

// ---------------- K2: attention, ONE block per (b,h), 8 waves, single-stage ----------------
// Defer-normalization + mask row hoisted out of the chunk loop (loop-invariant).
#define VPAD 212
__global__ __launch_bounds__(512) void attn_kernel(
    const u16* __restrict__ qg_all, const u16* __restrict__ kg_all, const u16* __restrict__ vg_all,
    const int* __restrict__ y, const float* __restrict__ mask_attn,
    u16* __restrict__ omid) {
    __shared__ __align__(16) u16 Ks[208 * 64];    // XOR-swizzled rows
    __shared__ __align__(16) u16 Vst[64 * VPAD];  // V^T, padded rows
    const int bh = blockIdx.x;
    const int b = bh / 12, h = bh % 12;
    const int tid = threadIdx.x, w = tid >> 6, l = tid & 63;
    const int dl = l & 15, g = l >> 4;
    const size_t base = (size_t)bh * 197 * 64;
    const u16* qg = qg_all + base;
    const u16* kg = kg_all + base;
    const u16* vg = vg_all + base;
    const short8 zero8 = {0, 0, 0, 0, 0, 0, 0, 0};
    const int ycls = y[b];

    // hoist mask row (per-lane slices d = db*16 + g*4, invariant across chunks)
    f32x4 mvh[4];
#pragma unroll
    for (int db = 0; db < 4; ++db)
        mvh[db] = *(const f32x4*)(mask_attn + ((size_t)ycls * 12 + h) * 64 + db * 16 + g * 4);

    for (int c = tid; c < 208 * 8; c += 512) {  // K tile, swizzled, zero pad rows 197..207
        int row = c >> 3, colb = (c & 7) * 16;
        short8 val = zero8;
        if (row < 197) val = *(const short8*)(kg + row * 64 + (c & 7) * 8);
        int bo = (row * 128 + colb) ^ ((row & 7) << 4);
        *(short8*)((char*)Ks + bo) = val;
    }
    for (int c = tid; c < 208 * 8; c += 512) {  // V transposed, zero pad keys 197..207
        int row = c >> 3, col = (c & 7) * 8;
        short8 val = zero8;
        if (row < 197) val = *(const short8*)(vg + row * 64 + col);
#pragma unroll
        for (int j = 0; j < 8; ++j) Vst[(col + j) * VPAD + row] = (u16)val[j];
    }
    __syncthreads();

    for (int ci = w; ci < 13; ci += 8) {  // 8 waves: 5 waves x2 chunks, 3 waves x1
        int qrow = ci * 16 + dl;
        const u16* qr = qg + (size_t)qrow * 64 + g * 8;
        short8 q0 = *(const short8*)(qr);
        short8 q1 = *(const short8*)(qr + 32);

        f32x4 sc[13];
#pragma unroll
        for (int jb = 0; jb < 13; ++jb) {
            int krow = jb * 16 + dl;
            int sw = (krow & 7) << 4;
            short8 k0 = *(const short8*)((const char*)Ks + ((krow * 128 + g * 16) ^ sw));
            short8 k1 = *(const short8*)((const char*)Ks + ((krow * 128 + 64 + g * 16) ^ sw));
            f32x4 t = {0.f, 0.f, 0.f, 0.f};
            t = __builtin_amdgcn_mfma_f32_16x16x32_bf16(k0, q0, t, 0, 0, 0);
            t = __builtin_amdgcn_mfma_f32_16x16x32_bf16(k1, q1, t, 0, 0, 0);
            sc[jb] = t;
        }
#pragma unroll
        for (int r = 0; r < 4; ++r)
            if (192 + g * 4 + r >= 197) sc[12][r] = -1e30f;

        float mx = -1e30f;
#pragma unroll
        for (int jb = 0; jb < 13; ++jb)
#pragma unroll
            for (int r = 0; r < 4; ++r) mx = fmaxf(mx, sc[jb][r]);
        mx = fmaxf(mx, __shfl_xor(mx, 16));
        mx = fmaxf(mx, __shfl_xor(mx, 32));
        float ssum = 0.f;
#pragma unroll
        for (int jb = 0; jb < 13; ++jb)
#pragma unroll
            for (int r = 0; r < 4; ++r) {
                float e = __expf(sc[jb][r] - mx);
                sc[jb][r] = e;
                ssum += e;
            }
        ssum += __shfl_xor(ssum, 16);
        ssum += __shfl_xor(ssum, 32);
        float inv = 1.0f / ssum;

        s16x4 pb[13];  // UNNORMALIZED P (exp values in [0,1])
#pragma unroll
        for (int jb = 0; jb < 13; ++jb) {
            s16x4 pv;
#pragma unroll
            for (int r = 0; r < 4; ++r) pv[r] = (short)f2bf(sc[jb][r]);
            pb[jb] = pv;
        }

        // Uniform whole-wave MFMA; only the store is per-lane predicated (R5 lesson).
        // inv is per-lane (output col q = dl) -> folded into the mask multiply.
#pragma unroll
        for (int db = 0; db < 4; ++db) {
            f32x4 o = {0.f, 0.f, 0.f, 0.f};
#pragma unroll
            for (int jb = 0; jb < 13; ++jb) {
                s16x4 va = *(const s16x4*)&Vst[(db * 16 + dl) * VPAD + jb * 16 + g * 4];
                o = MFMA16x16(va, pb[jb], o);
            }
            if (qrow < 197) {
                int d = db * 16 + g * 4;
                u16x4 ov;
#pragma unroll
                for (int r = 0; r < 4; ++r) ov[r] = f2bf(o[r] * inv * mvh[db][r]);
                *(u16x4*)(omid + ((size_t)(b * 256 + qrow)) * 768 + h * 64 + d) = ov;
            }
        }
    }
}

// ---------------- K4: proj GEMM, 256(M=197pad) x 64(N), BK=64 ----------------
__global__ __launch_bounds__(512, 4) void proj_gemm_kernel(
    const u16* __restrict__ A,          // omid [32][256][768] bf16
    const float* __restrict__ proj_w,   // [768][768] f32
    const float* __restrict__ mask_proj,// [100][768][768] f32
    const int* __restrict__ y,
    const float* __restrict__ bias,     // [768]
    float* __restrict__ out) {          // [32][197][768] f32
    __shared__ __align__(16) u16 Ap[2][256 * 64];  // 64 KB
    __shared__ __align__(16) u16 Bp[2][64 * 64];   // 16 KB
    const int tid = threadIdx.x;
    const int w = tid >> 6, l = tid & 63;
    const int wy = w >> 1, wx = w & 1;   // 4 M-waves x 2 N-waves (64x32 each)
    const int dl = l & 15, g4 = l >> 4;
    const int fr = (dl & 7) << 4;

    // bijective XCD chunking: nwg=384, q=48, r=0; bn-fast -> omid panel L2 reuse
    const int wg = blockIdx.x;
    const int id2 = (wg & 7) * 48 + (wg >> 3);
    const int b = id2 / 12, bn = id2 % 12;
    const size_t mbase = (size_t)y[b] * 589824;

    const int brow = tid >> 3;           // B-stage: N-row 0..63
    const int bcolf = (tid & 7) * 8;     // 8 f32 K-cols per thread
    const int bcb = bcolf * 2;           // byte col in bf16 LDS row
    const int bsw = (brow & 7) << 4;

    f32x4 pw[2], pm[2];

#define PROJ_LOADB(kt)                                                              \
    {                                                                               \
        size_t off = (size_t)(bn * 64 + brow) * 768 + (kt) + bcolf;                 \
        pw[0] = *(const f32x4*)(proj_w + off);                                      \
        pw[1] = *(const f32x4*)(proj_w + off + 4);                                  \
        pm[0] = *(const f32x4*)(mask_proj + mbase + off);                           \
        pm[1] = *(const f32x4*)(mask_proj + mbase + off + 4);                       \
    }

#define PROJ_WRITEB(bi)                                                             \
    {                                                                               \
        short8 o0;                                                                  \
        _Pragma("unroll")                                                           \
        for (int j = 0; j < 4; ++j) {                                               \
            o0[j] = (short)f2bf(pw[0][j] * pm[0][j]);                               \
            o0[4 + j] = (short)f2bf(pw[1][j] * pm[1][j]);                           \
        }                                                                           \
        *(short8*)((char*)Bp[bi] + brow * 128 + (bcb ^ bsw)) = o0;                  \
    }

#define PROJ_STAGEA(bi, kt)                                                         \
    {                                                                               \
        _Pragma("unroll")                                                           \
        for (int cc = 0; cc < 4; ++cc) {                                            \
            int c = cc * 512 + tid;                                                 \
            int row = c >> 3;                                                       \
            int cs = ((c & 7) << 4) ^ ((row & 7) << 4);                             \
            __builtin_amdgcn_global_load_lds(                                       \
                GPTR((const char*)(A + (size_t)(b * 256 + row) * 768 + (kt)) + cs), \
                LPTR((char*)Ap[bi] + c * 16), 16, 0, 0);                            \
        }                                                                           \
    }

    f32x4 acc[4][2] = {};
    PROJ_LOADB(0)
    PROJ_STAGEA(0, 0)
    PROJ_WRITEB(0)
    __syncthreads();
    int cur = 0;
#pragma unroll 1
    for (int t = 0; t < 12; ++t) {
        if (t < 11) {
            PROJ_STAGEA(cur ^ 1, (t + 1) * 64)  // async A prefetch
            PROJ_LOADB((t + 1) * 64)            // B f32 loads issue early...
        }
#pragma unroll
        for (int s = 0; s < 2; ++s) {
            const int ce = ((s << 6) | (g4 << 4)) ^ fr;
            short8 af[4], bf[2];
#pragma unroll
            for (int mi = 0; mi < 4; ++mi)
                af[mi] = *(const short8*)((const char*)Ap[cur] + (wy * 64 + mi * 16 + dl) * 128 + ce);
#pragma unroll
            for (int ni = 0; ni < 2; ++ni)
                bf[ni] = *(const short8*)((const char*)Bp[cur] + (wx * 32 + ni * 16 + dl) * 128 + ce);
#pragma unroll
            for (int mi = 0; mi < 4; ++mi)
#pragma unroll
                for (int ni = 0; ni < 2; ++ni)
                    acc[mi][ni] = __builtin_amdgcn_mfma_f32_16x16x32_bf16(af[mi], bf[ni], acc[mi][ni], 0, 0, 0);
        }
        if (t < 11) PROJ_WRITEB(cur ^ 1)        // ...convert+write late (latency hidden)
        __syncthreads();
        cur ^= 1;
    }

#pragma unroll
    for (int ni = 0; ni < 2; ++ni) {
        int col = bn * 64 + wx * 32 + ni * 16 + dl;
        float bv = bias[col];
#pragma unroll
        for (int mi = 0; mi < 4; ++mi) {
#pragma unroll
            for (int r = 0; r < 4; ++r) {
                int row = wy * 64 + mi * 16 + g4 * 4 + r;
                if (row < 197)
                    out[((size_t)b * 197 + row) * 768 + col] = acc[mi][ni][r] + bv;
            }
        }
    }
#undef PROJ_LOADB
#undef PROJ_WRITEB
#undef PROJ_STAGEA
}

extern "C" void kernel_launch(void* const* d_in, const int* in_sizes, int n_in,
                              void* d_out, int out_size, void* d_ws, size_t ws_size,
                              hipStream_t stream) {
    const float* x = (const float*)d_in[0];
    const int* y = (const int*)d_in[1];
    const float* qkv_w = (const float*)d_in[2];
    const float* qkv_b = (const float*)d_in[3];
    const float* proj_w = (const float*)d_in[4];
    const float* proj_b = (const float*)d_in[5];
    const float* mask_attn = (const float*)d_in[6];
    const float* mask_proj = (const float*)d_in[7];
    float* out = (float*)d_out;

    // workspace layout (bf16 = u16), ~55.3 MB
    u16* xb = (u16*)d_ws;                       // [6400][768]
    u16* wqkvb = xb + (size_t)6400 * 768;       // [2304][768]
    u16* qb = wqkvb + (size_t)2304 * 768;       // [76288][64]
    u16* kb = qb + (size_t)76288 * 64;
    u16* vb = kb + (size_t)76288 * 64;
    u16* omid = vb + (size_t)76288 * 64;        // [32][256][768]

    cvt_fused_kernel<<<6456, 256, 0, stream>>>(x, qkv_w, xb, wqkvb);
    qkv_gemm_kernel<<<225, 512, 0, stream>>>(xb, wqkvb, qkv_b, qb, kb, vb);
    attn_kernel<<<384, 512, 0, stream>>>(qb, kb, vb, y, mask_attn, omid);
    proj_gemm_kernel<<<384, 512, 0, stream>>>(omid, proj_w, mask_proj, y, proj_b, out);
}